// Round 1
// baseline (297.946 us; speedup 1.0000x reference)
//
#include <hip/hip_runtime.h>
#include <math.h>

#define BB 256
#define NNODE 90
#define FF 90
#define KK 10
#define DP 96
#define STR 97
#define NTOT (BB*NNODE)   // 23040

// ---------------- build adjacency ----------------
__global__ __launch_bounds__(256)
void build_A_kernel(const int* __restrict__ ei, const float* __restrict__ attr,
                    int E, float* __restrict__ A) {
    int e = blockIdx.x * 256 + threadIdx.x;
    if (e >= E) return;
    int s = ei[e];
    int d = ei[E + e];
    int g  = d / NNODE;
    int dl = d - g * NNODE;
    int sl = s - (s / NNODE) * NNODE;
    A[g * DP * DP + dl * DP + sl] = attr[e];
}

// ---------------- precompute folded classifier ----------------
// vlin[i] = sum_j lin_W[i][j]*cls_W[j]  (i<900)
// scal[0] = lin_b . cls_W + cls_b ; scal[1] = 1/||pool_p||
__global__ __launch_bounds__(256)
void prep_v_kernel(const float* __restrict__ linW, const float* __restrict__ linb,
                   const float* __restrict__ clsW, const float* __restrict__ clsb,
                   const float* __restrict__ poolp,
                   float* __restrict__ vlin, float* __restrict__ scal) {
    int b = blockIdx.x, tid = threadIdx.x;
    int lane = tid & 63, w = tid >> 6;
    if (b < 225) {
        int j = b * 4 + w;
        const float* row = linW + (size_t)j * 1801;
        float acc = 0.f;
        for (int c = lane; c < 1801; c += 64) acc += row[c] * clsW[c];
        for (int off = 32; off; off >>= 1) acc += __shfl_down(acc, off);
        if (lane == 0) vlin[j] = acc;
    } else {
        if (w == 0) {
            float acc = 0.f;
            for (int c = lane; c < 1801; c += 64) acc += linb[c] * clsW[c];
            for (int off = 32; off; off >>= 1) acc += __shfl_down(acc, off);
            if (lane == 0) scal[0] = acc + clsb[0];
        } else if (w == 1) {
            float acc = 0.f;
            for (int c = lane; c < 90; c += 64) acc += poolp[c] * poolp[c];
            for (int off = 32; off; off >>= 1) acc += __shfl_down(acc, off);
            if (lane == 0) scal[1] = rsqrtf(acc);
        }
    }
}

// ---------------- conv layer (one graph per block) ----------------
// H = relu(bias + BN(xin) @ Wr + A @ (BN(xin) @ Wm)), plus BN partial sums of H.
__global__ __launch_bounds__(256)
void conv_kernel(const float* __restrict__ xin,
                 const float* __restrict__ mu, const float* __restrict__ rsig, int apply_bn,
                 const float* __restrict__ A,
                 const float* __restrict__ Wm, const float* __restrict__ Wr,
                 const float* __restrict__ bias,
                 float* __restrict__ hout, float* __restrict__ gsum, float* __restrict__ gsq)
{
    extern __shared__ float smem[];
    float* sX = smem;             // [DP][STR]
    float* sW = sX + DP * STR;    // [DP][STR]  (Wm, then Wr)
    float* sM = sW + DP * STR;    // [DP][STR]
    float* sA = sM + DP * STR;    // [DP][STR]
    float* sSum = sA + DP * STR;  // [DP]
    float* sSq  = sSum + DP;      // [DP]

    const int g = blockIdx.x, tid = threadIdx.x;
    if (tid < DP) { sSum[tid] = 0.f; sSq[tid] = 0.f; }

    // stage X (BN applied), A, Wm
    for (int idx = tid; idx < DP * DP; idx += 256) {
        int d = idx / DP, k = idx - (idx / DP) * DP;
        float xv = 0.f;
        if (d < NNODE && k < FF) {
            xv = xin[(g * NNODE + d) * FF + k];
            if (apply_bn) xv = (xv - mu[k]) * rsig[k];
        }
        sX[d * STR + k] = xv;
        sA[d * STR + k] = A[g * DP * DP + idx];
        sW[d * STR + k] = (d < FF && k < FF) ? Wm[d * FF + k] : 0.f;
    }
    __syncthreads();

    const int fg = tid & 15, dg = tid >> 4;
    const int d0 = dg * 6, f0 = fg * 6;

    // phase 1: M = X @ Wm (6x6 register tile)
    float acc[6][6];
#pragma unroll
    for (int i = 0; i < 6; i++)
#pragma unroll
        for (int j = 0; j < 6; j++) acc[i][j] = 0.f;

#pragma unroll 2
    for (int k = 0; k < DP; k++) {
        float xr[6], wc[6];
#pragma unroll
        for (int i = 0; i < 6; i++) xr[i] = sX[(d0 + i) * STR + k];
#pragma unroll
        for (int j = 0; j < 6; j++) wc[j] = sW[k * STR + f0 + j];
#pragma unroll
        for (int i = 0; i < 6; i++)
#pragma unroll
            for (int j = 0; j < 6; j++) acc[i][j] = fmaf(xr[i], wc[j], acc[i][j]);
    }
#pragma unroll
    for (int i = 0; i < 6; i++)
#pragma unroll
        for (int j = 0; j < 6; j++) sM[(d0 + i) * STR + f0 + j] = acc[i][j];
    __syncthreads();   // everyone done reading Wm and writing M

    // reload sW with Wr
    for (int idx = tid; idx < DP * DP; idx += 256) {
        int d = idx / DP, k = idx - (idx / DP) * DP;
        sW[d * STR + k] = (d < FF && k < FF) ? Wr[d * FF + k] : 0.f;
    }
    __syncthreads();

    // phase 2: H = relu(bias + X@Wr + A@M)
    float acc2[6][6];
#pragma unroll
    for (int j = 0; j < 6; j++) {
        int f = f0 + j;
        float bj = (f < FF) ? bias[f] : 0.f;
#pragma unroll
        for (int i = 0; i < 6; i++) acc2[i][j] = bj;
    }
#pragma unroll 2
    for (int k = 0; k < DP; k++) {
        float xr[6], ar[6], wc[6], mc[6];
#pragma unroll
        for (int i = 0; i < 6; i++) { xr[i] = sX[(d0 + i) * STR + k]; ar[i] = sA[(d0 + i) * STR + k]; }
#pragma unroll
        for (int j = 0; j < 6; j++) { wc[j] = sW[k * STR + f0 + j]; mc[j] = sM[k * STR + f0 + j]; }
#pragma unroll
        for (int i = 0; i < 6; i++)
#pragma unroll
            for (int j = 0; j < 6; j++)
                acc2[i][j] += xr[i] * wc[j] + ar[i] * mc[j];
    }

    float csum[6], csq[6];
#pragma unroll
    for (int j = 0; j < 6; j++) { csum[j] = 0.f; csq[j] = 0.f; }
    if (d0 < NNODE && f0 < FF) {
#pragma unroll
        for (int i = 0; i < 6; i++) {
            int d = d0 + i;
            if (d < NNODE) {
#pragma unroll
                for (int j = 0; j < 6; j++) {
                    int f = f0 + j;
                    if (f < FF) {
                        float v = fmaxf(acc2[i][j], 0.f);
                        hout[(g * NNODE + d) * FF + f] = v;
                        csum[j] += v; csq[j] += v * v;
                    }
                }
            }
        }
#pragma unroll
        for (int j = 0; j < 6; j++) {
            int f = f0 + j;
            if (f < FF) { atomicAdd(&sSum[f], csum[j]); atomicAdd(&sSq[f], csq[j]); }
        }
    }
    __syncthreads();
    if (tid < FF) { atomicAdd(&gsum[tid], sSum[tid]); atomicAdd(&gsq[tid], sSq[tid]); }
}

// ---------------- BN finalize ----------------
__global__ __launch_bounds__(128)
void finalize_bn_kernel(const float* __restrict__ gsum, const float* __restrict__ gsq,
                        float* __restrict__ mu, float* __restrict__ rs) {
    int f = threadIdx.x;
    if (f < FF) {
        float m = gsum[f] / (float)NTOT;
        float v = gsq[f] / (float)NTOT - m * m;
        mu[f] = m;
        rs[f] = rsqrtf(v + 1e-5f);
    }
}

// ---------------- pooling + classifier ----------------
__global__ __launch_bounds__(128)
void final_kernel(const float* __restrict__ h2,
                  const float* __restrict__ mu2, const float* __restrict__ rs2,
                  const float* __restrict__ poolp,
                  const float* __restrict__ vlin, const float* __restrict__ scal,
                  float* __restrict__ out)
{
    __shared__ float sScore[NNODE];
    __shared__ int   sIdx[KK];
    __shared__ float sVal[KK];
    __shared__ float sRed[2];
    int g = blockIdx.x, tid = threadIdx.x;

    if (tid < NNODE) {
        const float* row = h2 + (size_t)(g * NNODE + tid) * FF;
        float s = 0.f;
        for (int f = 0; f < FF; f++) s += (row[f] - mu2[f]) * rs2[f] * poolp[f];
        sScore[tid] = 0.7f * tanhf(s * scal[1]);
    }
    __syncthreads();

    if (tid == 0) {
        for (int k = 0; k < KK; k++) {
            float best = -1e30f; int bi = 0;
            for (int d = 0; d < NNODE; d++) {
                if (sScore[d] > best) { best = sScore[d]; bi = d; }
            }
            sIdx[k] = bi; sVal[k] = best;
            sScore[bi] = -1e30f;
        }
    }
    __syncthreads();

    if (tid < KK) out[BB + g * KK + tid] = (float)(g * NNODE + sIdx[tid]);

    float acc = 0.f;
    for (int j = tid; j < KK * FF; j += 128) {
        int k = j / FF, f = j - (j / FF) * FF;
        int node = g * NNODE + sIdx[k];
        float xv = (h2[(size_t)node * FF + f] - mu2[f]) * rs2[f];
        acc += xv * sVal[k] * vlin[j];
    }
    for (int off = 32; off; off >>= 1) acc += __shfl_down(acc, off);
    if ((tid & 63) == 0) sRed[tid >> 6] = acc;
    __syncthreads();
    if (tid == 0) {
        float tot = sRed[0] + sRed[1] + scal[0];
        out[g] = 1.f / (1.f + expf(-tot));
    }
}

// ---------------- host launch ----------------
extern "C" void kernel_launch(void* const* d_in, const int* in_sizes, int n_in,
                              void* d_out, int out_size, void* d_ws, size_t ws_size,
                              hipStream_t stream) {
    const float* x    = (const float*)d_in[0];
    const int*   ei   = (const int*)  d_in[1];
    const float* attr = (const float*)d_in[2];
    // d_in[3] = batch (unused; graph id derived from node index)
    const float* W1r  = (const float*)d_in[4];
    const float* W1m  = (const float*)d_in[5];
    const float* b1   = (const float*)d_in[6];
    const float* W2r  = (const float*)d_in[7];
    const float* W2m  = (const float*)d_in[8];
    const float* b2   = (const float*)d_in[9];
    const float* poolp= (const float*)d_in[10];
    const float* linW = (const float*)d_in[11];
    const float* linb = (const float*)d_in[12];
    const float* clsW = (const float*)d_in[13];
    const float* clsb = (const float*)d_in[14];
    const int E = in_sizes[2];

    float* ws   = (float*)d_ws;
    float* A    = ws;                       // 256*96*96 = 2,359,296
    float* h1   = A + BB * DP * DP;         // 23040*90 = 2,073,600
    float* h2   = h1 + NTOT * FF;           // 2,073,600
    float* stats= h2 + NTOT * FF;           // 768 floats
    float* gsum1 = stats;        float* gsq1 = stats + 96;
    float* mu1   = stats + 192;  float* rs1  = stats + 288;
    float* gsum2 = stats + 384;  float* gsq2 = stats + 480;
    float* mu2   = stats + 576;  float* rs2  = stats + 672;
    float* vlin = stats + 768;              // 900
    float* scal = vlin + 900;               // 2

    hipMemsetAsync(A, 0, (size_t)BB * DP * DP * sizeof(float), stream);
    hipMemsetAsync(stats, 0, 768 * sizeof(float), stream);

    build_A_kernel<<<(E + 255) / 256, 256, 0, stream>>>(ei, attr, E, A);
    prep_v_kernel<<<226, 256, 0, stream>>>(linW, linb, clsW, clsb, poolp, vlin, scal);

    const size_t smem = (size_t)(4 * DP * STR + 2 * DP) * sizeof(float); // 149,760 B
    conv_kernel<<<BB, 256, smem, stream>>>(x, mu1, rs1, 0, A, W1m, W1r, b1, h1, gsum1, gsq1);
    finalize_bn_kernel<<<1, 128, 0, stream>>>(gsum1, gsq1, mu1, rs1);
    conv_kernel<<<BB, 256, smem, stream>>>(h1, mu1, rs1, 1, A, W2m, W2r, b2, h2, gsum2, gsq2);
    finalize_bn_kernel<<<1, 128, 0, stream>>>(gsum2, gsq2, mu2, rs2);

    final_kernel<<<BB, 128, 0, stream>>>(h2, mu2, rs2, poolp, vlin, scal, (float*)d_out);
}

// Round 2
// 285.847 us; speedup vs baseline: 1.0423x; 1.0423x over previous
//
#include <hip/hip_runtime.h>
#include <math.h>

#define BB 256
#define NNODE 90
#define FF 90
#define KK 10
#define NTOT (BB*NNODE)   // 23040
#define EPG 8010          // edges per graph (90*89)

// ---------------- precompute folded classifier ----------------
// vlin[i] = sum_j lin_W[i][j]*cls_W[j]  (i<900)
// scal[0] = lin_b . cls_W + cls_b ; scal[1] = 1/||pool_p||
__global__ __launch_bounds__(256)
void prep_v_kernel(const float* __restrict__ linW, const float* __restrict__ linb,
                   const float* __restrict__ clsW, const float* __restrict__ clsb,
                   const float* __restrict__ poolp,
                   float* __restrict__ vlin, float* __restrict__ scal) {
    int b = blockIdx.x, tid = threadIdx.x;
    int lane = tid & 63, w = tid >> 6;
    if (b < 225) {
        int j = b * 4 + w;
        const float* row = linW + (size_t)j * 1801;
        float acc = 0.f;
        for (int c = lane; c < 1801; c += 64) acc += row[c] * clsW[c];
        for (int off = 32; off; off >>= 1) acc += __shfl_down(acc, off);
        if (lane == 0) vlin[j] = acc;
    } else {
        if (w == 0) {
            float acc = 0.f;
            for (int c = lane; c < 1801; c += 64) acc += linb[c] * clsW[c];
            for (int off = 32; off; off >>= 1) acc += __shfl_down(acc, off);
            if (lane == 0) scal[0] = acc + clsb[0];
        } else if (w == 1) {
            float acc = 0.f;
            for (int c = lane; c < 90; c += 64) acc += poolp[c] * poolp[c];
            for (int off = 32; off; off >>= 1) acc += __shfl_down(acc, off);
            if (lane == 0) scal[1] = rsqrtf(acc);
        }
    }
}

// ---------------- k1: M = BN(X)@Wm, R = BN(X)@Wr ----------------
// grid = 360 rowblocks x 2 colhalves; block 256 = 16tx x 16ty
// thread tile: 4 rows x 3 cols, both outputs. K padded to 96.
__global__ __launch_bounds__(256, 2)
void k1_gemm(const float* __restrict__ xin,
             const float* __restrict__ gsum, const float* __restrict__ gsq, int apply_bn,
             const float* __restrict__ Wm, const float* __restrict__ Wr,
             float* __restrict__ M, float* __restrict__ R)
{
    __shared__ float sMu[96], sRs[96];
    __shared__ float sXT[96 * 68];    // [k][r] transposed, stride 68
    __shared__ float sWmT[48 * 98];   // [c][k] transposed, stride 98
    __shared__ float sWrT[48 * 98];

    const int tid = threadIdx.x;
    const int rb = blockIdx.x >> 1, ch = blockIdx.x & 1;
    const int row0 = rb * 64, col0 = ch * 48;

    if (tid < 96) {
        float m = 0.f, r = 1.f;
        if (apply_bn && tid < 90) {
            m = gsum[tid] * (1.f / NTOT);
            float v = gsq[tid] * (1.f / NTOT) - m * m;
            r = rsqrtf(v + 1e-5f);
        }
        sMu[tid] = m; sRs[tid] = r;
    }
    __syncthreads();

    // stage X transposed (coalesced global read; 8-way LDS write alias ok)
    for (int idx = tid; idx < 64 * 96; idx += 256) {
        int r = idx / 96, k = idx - (idx / 96) * 96;
        float v = 0.f;
        if (k < 90) v = (xin[(row0 + r) * 90 + k] - sMu[k]) * sRs[k];
        sXT[k * 68 + r] = v;
    }
    // stage W transposed (gathered global read from L2-hot W; conflict-free LDS write)
    for (int idx = tid; idx < 48 * 96; idx += 256) {
        int c = idx / 96, k = idx - (idx / 96) * 96;
        int col = col0 + c;
        float vm = 0.f, vr = 0.f;
        if (k < 90 && col < 90) { vm = Wm[k * 90 + col]; vr = Wr[k * 90 + col]; }
        sWmT[c * 98 + k] = vm;
        sWrT[c * 98 + k] = vr;
    }
    __syncthreads();

    const int tx = tid & 15, ty = tid >> 4;
    const int r0 = ty * 4, c0 = tx * 3;
    float accM[4][3] = {{0.f}}, accR[4][3] = {{0.f}};
    const float* pX  = sXT + r0;
    const float* pWm = sWmT + c0 * 98;
    const float* pWr = sWrT + c0 * 98;

#pragma unroll 4
    for (int k = 0; k < 96; k += 2) {
        float4 x0 = *(const float4*)(pX + k * 68);
        float4 x1 = *(const float4*)(pX + (k + 1) * 68);
        float2 wm[3], wr[3];
#pragma unroll
        for (int j = 0; j < 3; j++) {
            wm[j] = *(const float2*)(pWm + j * 98 + k);
            wr[j] = *(const float2*)(pWr + j * 98 + k);
        }
        float xa0[4] = {x0.x, x0.y, x0.z, x0.w};
        float xa1[4] = {x1.x, x1.y, x1.z, x1.w};
#pragma unroll
        for (int i = 0; i < 4; i++) {
#pragma unroll
            for (int j = 0; j < 3; j++) {
                accM[i][j] = fmaf(xa0[i], wm[j].x, fmaf(xa1[i], wm[j].y, accM[i][j]));
                accR[i][j] = fmaf(xa0[i], wr[j].x, fmaf(xa1[i], wr[j].y, accR[i][j]));
            }
        }
    }

#pragma unroll
    for (int i = 0; i < 4; i++) {
        int row = row0 + r0 + i;
        float* pm = M + (size_t)row * 96 + col0 + c0;
        float* pr = R + (size_t)row * 96 + col0 + c0;
#pragma unroll
        for (int j = 0; j < 3; j++) { pm[j] = accM[i][j]; pr[j] = accR[i][j]; }
    }
}

// ---------------- k2: H = relu(bias + R + A@M) + BN stats ----------------
// grid = 256 graphs x 2 row-halves; block 256 = 16tx x 16ty
// thread tile: 3 rows x 6 cols. A staged straight from edge_attr.
__global__ __launch_bounds__(256, 2)
void k2_graph(const float* __restrict__ attr,
              const float* __restrict__ Mbuf, const float* __restrict__ Rbuf,
              const float* __restrict__ bias,
              float* __restrict__ hout, float* __restrict__ gsum, float* __restrict__ gsq)
{
    __shared__ float sA[48 * 98];    // [dl][s]  stride 98
    __shared__ float sMT[96 * 98];   // [f][k]   stride 98
    __shared__ float sSum[96], sSq[96];

    const int tid = threadIdx.x;
    const int g = blockIdx.x >> 1, hh = blockIdx.x & 1;
    const int d0g = hh * 48;

    if (tid < 96) { sSum[tid] = 0.f; sSq[tid] = 0.f; }

    // stage A[dl][s] = attr(s -> d) ; coalesced attr reads
    const float* ag = attr + (size_t)g * EPG;
    for (int idx = tid; idx < 96 * 48; idx += 256) {
        int s = idx / 48, dl = idx - (idx / 48) * 48;
        int d = d0g + dl;
        float v = 0.f;
        if (s < 90 && d < 90 && d != s) v = ag[s * 89 + (d > s ? d - 1 : d)];
        sA[dl * 98 + s] = v;
    }
    // stage M transposed [f][k]
    for (int idx = tid; idx < 96 * 96; idx += 256) {
        int c = idx / 96, kk = idx - (idx / 96) * 96;
        float v = (kk < 90) ? Mbuf[(size_t)(g * NNODE + kk) * 96 + c] : 0.f;
        sMT[c * 98 + kk] = v;
    }
    __syncthreads();

    const int tx = tid & 15, ty = tid >> 4;
    const int dl0 = ty * 3, c0 = tx * 6;
    float acc[3][6] = {{0.f}};
    const float* pA = sA + dl0 * 98;
    const float* pM = sMT + c0 * 98;

#pragma unroll 4
    for (int k = 0; k < 96; k += 2) {
        float2 a[3], m[6];
#pragma unroll
        for (int i = 0; i < 3; i++) a[i] = *(const float2*)(pA + i * 98 + k);
#pragma unroll
        for (int j = 0; j < 6; j++) m[j] = *(const float2*)(pM + j * 98 + k);
#pragma unroll
        for (int i = 0; i < 3; i++)
#pragma unroll
            for (int j = 0; j < 6; j++)
                acc[i][j] = fmaf(a[i].x, m[j].x, fmaf(a[i].y, m[j].y, acc[i][j]));
    }

    float csum[6] = {0.f}, csq[6] = {0.f};
#pragma unroll
    for (int i = 0; i < 3; i++) {
        int d = d0g + dl0 + i;
        if (d < 90) {
            int row = g * NNODE + d;
#pragma unroll
            for (int j = 0; j < 6; j++) {
                int f = c0 + j;
                if (f < 90) {
                    float v = bias[f] + Rbuf[(size_t)row * 96 + f] + acc[i][j];
                    v = fmaxf(v, 0.f);
                    hout[(size_t)row * 90 + f] = v;
                    csum[j] += v; csq[j] += v * v;
                }
            }
        }
    }
    if (d0g + dl0 < 90) {
#pragma unroll
        for (int j = 0; j < 6; j++) {
            int f = c0 + j;
            if (f < 90) { atomicAdd(&sSum[f], csum[j]); atomicAdd(&sSq[f], csq[j]); }
        }
    }
    __syncthreads();
    if (tid < 90) { atomicAdd(&gsum[tid], sSum[tid]); atomicAdd(&gsq[tid], sSq[tid]); }
}

// ---------------- pooling + classifier ----------------
__global__ __launch_bounds__(256)
void final_kernel(const float* __restrict__ h2,
                  const float* __restrict__ gsum, const float* __restrict__ gsq,
                  const float* __restrict__ poolp,
                  const float* __restrict__ vlin, const float* __restrict__ scal,
                  float* __restrict__ out)
{
    __shared__ float sXN[90 * 91];
    __shared__ float sMu[96], sRs[96], sP[96];
    __shared__ float sScore[90];
    __shared__ int   sIdx[KK];
    __shared__ float sVal[KK];
    __shared__ float sRed[4];
    const int g = blockIdx.x, tid = threadIdx.x;

    if (tid < 90) {
        float m = gsum[tid] * (1.f / NTOT);
        float v = gsq[tid] * (1.f / NTOT) - m * m;
        sMu[tid] = m; sRs[tid] = rsqrtf(v + 1e-5f);
        sP[tid] = poolp[tid];
    }
    __syncthreads();

    const float* hg = h2 + (size_t)g * (NNODE * FF);
    for (int idx = tid; idx < 90 * 90; idx += 256) {
        int d = idx / 90, f = idx - (idx / 90) * 90;
        sXN[d * 91 + f] = (hg[idx] - sMu[f]) * sRs[f];
    }
    __syncthreads();

    if (tid < 90) {
        float s = 0.f;
        for (int f = 0; f < 90; f++) s += sXN[tid * 91 + f] * sP[f];
        sScore[tid] = 0.7f * tanhf(s * scal[1]);
    }
    __syncthreads();

    // wave-parallel top-10 (ties -> lower index, matching lax.top_k)
    if (tid < 64) {
        float va = sScore[tid];
        float vb = (tid + 64 < 90) ? sScore[tid + 64] : -1e30f;
        int ia = tid, ib = tid + 64;
        for (int k = 0; k < KK; k++) {
            float v; int i;
            if (va >= vb) { v = va; i = ia; } else { v = vb; i = ib; }
            for (int off = 1; off < 64; off <<= 1) {
                float v2 = __shfl_xor(v, off);
                int   i2 = __shfl_xor(i, off);
                if (v2 > v || (v2 == v && i2 < i)) { v = v2; i = i2; }
            }
            if (tid == 0) { sIdx[k] = i; sVal[k] = v; }
            if (i == ia) va = -1e30f;
            if (i == ib) vb = -1e30f;
        }
    }
    __syncthreads();

    if (tid < KK) out[BB + g * KK + tid] = (float)(g * NNODE + sIdx[tid]);

    float acc = 0.f;
    for (int j = tid; j < KK * FF; j += 256) {
        int k = j / 90, f = j - (j / 90) * 90;
        acc += sXN[sIdx[k] * 91 + f] * sVal[k] * vlin[j];
    }
    for (int off = 32; off; off >>= 1) acc += __shfl_down(acc, off);
    if ((tid & 63) == 0) sRed[tid >> 6] = acc;
    __syncthreads();
    if (tid == 0) {
        float tot = sRed[0] + sRed[1] + sRed[2] + sRed[3] + scal[0];
        out[g] = 1.f / (1.f + expf(-tot));
    }
}

// ---------------- host launch ----------------
extern "C" void kernel_launch(void* const* d_in, const int* in_sizes, int n_in,
                              void* d_out, int out_size, void* d_ws, size_t ws_size,
                              hipStream_t stream) {
    const float* x    = (const float*)d_in[0];
    const float* attr = (const float*)d_in[2];
    const float* W1r  = (const float*)d_in[4];
    const float* W1m  = (const float*)d_in[5];
    const float* b1   = (const float*)d_in[6];
    const float* W2r  = (const float*)d_in[7];
    const float* W2m  = (const float*)d_in[8];
    const float* b2   = (const float*)d_in[9];
    const float* poolp= (const float*)d_in[10];
    const float* linW = (const float*)d_in[11];
    const float* linb = (const float*)d_in[12];
    const float* clsW = (const float*)d_in[13];
    const float* clsb = (const float*)d_in[14];

    float* ws = (float*)d_ws;
    float* M    = ws;                     // 23040*96 = 2,211,840
    float* R    = M + (size_t)NTOT * 96;  // 2,211,840
    float* h    = R + (size_t)NTOT * 96;  // 23040*90 = 2,073,600 (shared h1/h2)
    float* stats= h + (size_t)NTOT * 90;  // 384
    float* gsum1 = stats;        float* gsq1 = stats + 96;
    float* gsum2 = stats + 192;  float* gsq2 = stats + 288;
    float* vlin = stats + 384;            // 900
    float* scal = vlin + 900;             // 2

    hipMemsetAsync(stats, 0, 384 * sizeof(float), stream);
    prep_v_kernel<<<226, 256, 0, stream>>>(linW, linb, clsW, clsb, poolp, vlin, scal);

    // layer 1
    k1_gemm<<<720, 256, 0, stream>>>(x, gsum1, gsq1, 0, W1m, W1r, M, R);
    k2_graph<<<512, 256, 0, stream>>>(attr, M, R, b1, h, gsum1, gsq1);
    // layer 2 (BN of h via gsum1/gsq1 applied on read)
    k1_gemm<<<720, 256, 0, stream>>>(h, gsum1, gsq1, 1, W2m, W2r, M, R);
    k2_graph<<<512, 256, 0, stream>>>(attr, M, R, b2, h, gsum2, gsq2);

    final_kernel<<<BB, 256, 0, stream>>>(h, gsum2, gsq2, poolp, vlin, scal, (float*)d_out);
}

// Round 4
// 197.134 us; speedup vs baseline: 1.5114x; 1.4500x over previous
//
#include <hip/hip_runtime.h>
#include <math.h>

#define NG   90
#define PD   96
#define STRD 100
#define KK   10
#define NB   256
#define NTOT (NB*NG)   // 23040
#define EPG  8010
#define SM_FLOATS (4*PD*STRD + 4*96)   // 38784 floats = 155,136 B

// ---------------- precompute folded classifier ----------------
__global__ __launch_bounds__(256)
void prep_v_kernel(const float* __restrict__ linW, const float* __restrict__ linb,
                   const float* __restrict__ clsW, const float* __restrict__ clsb,
                   const float* __restrict__ poolp,
                   float* __restrict__ vlin, float* __restrict__ scal) {
    int b = blockIdx.x, tid = threadIdx.x;
    int lane = tid & 63, w = tid >> 6;
    if (b < 225) {
        int j = b * 4 + w;
        const float* row = linW + (size_t)j * 1801;
        float acc = 0.f;
        for (int c = lane; c < 1801; c += 64) acc += row[c] * clsW[c];
        for (int off = 32; off; off >>= 1) acc += __shfl_down(acc, off);
        if (lane == 0) vlin[j] = acc;
    } else {
        if (w == 0) {
            float acc = 0.f;
            for (int c = lane; c < 1801; c += 64) acc += linb[c] * clsW[c];
            for (int off = 32; off; off >>= 1) acc += __shfl_down(acc, off);
            if (lane == 0) scal[0] = acc + clsb[0];
        } else if (w == 1) {
            float acc = 0.f;
            for (int c = lane; c < NG; c += 64) acc += poolp[c] * poolp[c];
            for (int off = 32; off; off >>= 1) acc += __shfl_down(acc, off);
            if (lane == 0) scal[1] = rsqrtf(acc);
        }
    }
}

// ---------------- one conv+BN-stats layer, one graph per block ----------------
__global__ __launch_bounds__(1024, 4)
void layer_kernel(const float* __restrict__ xin, const float* __restrict__ gsIn, int apply_bn,
                  const float* __restrict__ attr,
                  const float* __restrict__ Wm, const float* __restrict__ Wr,
                  const float* __restrict__ bias,
                  float* __restrict__ hout, float* __restrict__ gsOut)
{
    extern __shared__ float sm[];
    float* sX   = sm;                 // [96][100]  BN(x)
    float* sA   = sX + PD * STRD;     // [96][100]  A[d][s]
    float* sM   = sA + PD * STRD;     // [96][100]  M^T[c][r]
    float* sW   = sM + PD * STRD;     // [96][100]  W^T[c][k]
    float* sSum = sW + PD * STRD;     // [96]
    float* sSq  = sSum + 96;
    float* sMu  = sSq + 96;
    float* sRs  = sMu + 96;

    const int g = blockIdx.x, tid = threadIdx.x;
    const int lane = tid & 63, wave = tid >> 6;
    const int wr = wave >> 2, wc = wave & 3;
    const int lr = lane >> 3, lc = lane & 7;
    const int r0 = (wr * 8 + lr) * 3, c0 = (wc * 8 + lc) * 3;

    if (tid < 96) {
        sSum[tid] = 0.f; sSq[tid] = 0.f;
        float m = 0.f, r = 1.f;
        if (apply_bn && tid < NG) {
            m = gsIn[tid] * (1.f / NTOT);
            float v = gsIn[96 + tid] * (1.f / NTOT) - m * m;
            r = rsqrtf(v + 1e-5f);
        }
        sMu[tid] = m; sRs[tid] = r;
    }
    __syncthreads();   // B0: sMu/sRs ready

    // stage X (BN applied), A (closed-form from attr), Wm^T
    for (int idx = tid; idx < PD * PD; idx += 1024) {
        int r = idx / PD, k = idx - (idx / PD) * PD;
        float v = 0.f;
        if (r < NG && k < NG) v = (xin[(g * NG + r) * NG + k] - sMu[k]) * sRs[k];
        sX[r * STRD + k] = v;
    }
    for (int idx = tid; idx < PD * PD; idx += 1024) {
        int s = idx / PD, d = idx - (idx / PD) * PD;
        float v = 0.f;
        if (s < NG && d < NG && d != s) v = attr[g * EPG + s * 89 + (d > s ? d - 1 : d)];
        sA[d * STRD + s] = v;
    }
    for (int idx = tid; idx < PD * PD; idx += 1024) {
        int k = idx / PD, c = idx - (idx / PD) * PD;
        float v = (k < NG && c < NG) ? Wm[k * NG + c] : 0.f;
        sW[c * STRD + k] = v;
    }
    // prefetch Wr (reg-staged; written to sW after GEMM1) and bias
    float wrg[9];
#pragma unroll
    for (int t = 0; t < 9; t++) {
        int idx = tid + t * 1024;
        int k = idx / PD, c = idx - (idx / PD) * PD;
        wrg[t] = (k < NG && c < NG) ? Wr[k * NG + c] : 0.f;
    }
    float bj[3];
#pragma unroll
    for (int j = 0; j < 3; j++) bj[j] = (c0 + j < NG) ? bias[c0 + j] : 0.f;
    __syncthreads();   // B1

    // ---- GEMM1: M = X @ Wm ----
    float accM[3][3] = {{0.f,0.f,0.f},{0.f,0.f,0.f},{0.f,0.f,0.f}};
    {
        const float* pX = sX + r0 * STRD;
        const float* pW = sW + c0 * STRD;
#pragma unroll 3
        for (int k = 0; k < PD; k += 4) {
            float4 xv[3], wv[3];
#pragma unroll
            for (int i = 0; i < 3; i++) xv[i] = *(const float4*)(pX + i * STRD + k);
#pragma unroll
            for (int j = 0; j < 3; j++) wv[j] = *(const float4*)(pW + j * STRD + k);
#pragma unroll
            for (int i = 0; i < 3; i++)
#pragma unroll
                for (int j = 0; j < 3; j++) {
                    accM[i][j] = fmaf(xv[i].x, wv[j].x, accM[i][j]);
                    accM[i][j] = fmaf(xv[i].y, wv[j].y, accM[i][j]);
                    accM[i][j] = fmaf(xv[i].z, wv[j].z, accM[i][j]);
                    accM[i][j] = fmaf(xv[i].w, wv[j].w, accM[i][j]);
                }
        }
    }
    // write M^T
#pragma unroll
    for (int j = 0; j < 3; j++)
#pragma unroll
        for (int i = 0; i < 3; i++)
            sM[(c0 + j) * STRD + (r0 + i)] = accM[i][j];
    __syncthreads();   // B2: GEMM1 sW reads done, sM visible

    // sW <- Wr^T (from regs; global latency already hidden under GEMM1)
#pragma unroll
    for (int t = 0; t < 9; t++) {
        int idx = tid + t * 1024;
        int k = idx / PD, c = idx - (idx / PD) * PD;
        sW[c * STRD + k] = wrg[t];
    }
    __syncthreads();   // B3

    // ---- GEMM2: h = bias + X@Wr + A@M ----
    float h[3][3];
#pragma unroll
    for (int j = 0; j < 3; j++)
#pragma unroll
        for (int i = 0; i < 3; i++) h[i][j] = bj[j];
    {
        const float* pX = sX + r0 * STRD;
        const float* pA = sA + r0 * STRD;
        const float* pW = sW + c0 * STRD;
        const float* pM = sM + c0 * STRD;
#pragma unroll 2
        for (int k = 0; k < PD; k += 4) {
            float4 xv[3], av[3], wv[3], mv[3];
#pragma unroll
            for (int i = 0; i < 3; i++) {
                xv[i] = *(const float4*)(pX + i * STRD + k);
                av[i] = *(const float4*)(pA + i * STRD + k);
            }
#pragma unroll
            for (int j = 0; j < 3; j++) {
                wv[j] = *(const float4*)(pW + j * STRD + k);
                mv[j] = *(const float4*)(pM + j * STRD + k);
            }
#pragma unroll
            for (int i = 0; i < 3; i++)
#pragma unroll
                for (int j = 0; j < 3; j++) {
                    h[i][j] = fmaf(xv[i].x, wv[j].x, h[i][j]);
                    h[i][j] = fmaf(xv[i].y, wv[j].y, h[i][j]);
                    h[i][j] = fmaf(xv[i].z, wv[j].z, h[i][j]);
                    h[i][j] = fmaf(xv[i].w, wv[j].w, h[i][j]);
                    h[i][j] = fmaf(av[i].x, mv[j].x, h[i][j]);
                    h[i][j] = fmaf(av[i].y, mv[j].y, h[i][j]);
                    h[i][j] = fmaf(av[i].z, mv[j].z, h[i][j]);
                    h[i][j] = fmaf(av[i].w, mv[j].w, h[i][j]);
                }
        }
    }

    // relu + global write + per-column partial sums
    float cs[3] = {0.f,0.f,0.f}, cq[3] = {0.f,0.f,0.f};
#pragma unroll
    for (int i = 0; i < 3; i++) {
        int r = r0 + i;
        if (r < NG) {
#pragma unroll
            for (int j = 0; j < 3; j++) {
                int c = c0 + j;
                float v = fmaxf(h[i][j], 0.f);
                if (c < NG) {
                    hout[(size_t)(g * NG + r) * NG + c] = v;
                    cs[j] += v; cq[j] += v * v;
                }
            }
        }
    }
    // reduce over the wave's 8 row-groups (lane bits 3..5)
#pragma unroll
    for (int m = 8; m < 64; m <<= 1) {
#pragma unroll
        for (int j = 0; j < 3; j++) {
            cs[j] += __shfl_xor(cs[j], m);
            cq[j] += __shfl_xor(cq[j], m);
        }
    }
    if (lr == 0) {
#pragma unroll
        for (int j = 0; j < 3; j++) {
            int c = c0 + j;
            if (c < NG) { atomicAdd(&sSum[c], cs[j]); atomicAdd(&sSq[c], cq[j]); }
        }
    }
    __syncthreads();
    if (tid < NG) { atomicAdd(&gsOut[tid], sSum[tid]); atomicAdd(&gsOut[96 + tid], sSq[tid]); }
}

// ---------------- pooling + classifier ----------------
__global__ __launch_bounds__(256)
void final_kernel(const float* __restrict__ h2,
                  const float* __restrict__ gsum, const float* __restrict__ gsq,
                  const float* __restrict__ poolp,
                  const float* __restrict__ vlin, const float* __restrict__ scal,
                  float* __restrict__ out)
{
    __shared__ float sXN[NG * 91];
    __shared__ float sMu[96], sRs[96], sP[96];
    __shared__ float sScore[NG];
    __shared__ int   sIdx[KK];
    __shared__ float sVal[KK];
    __shared__ float sRed[4];
    const int g = blockIdx.x, tid = threadIdx.x;

    if (tid < NG) {
        float m = gsum[tid] * (1.f / NTOT);
        float v = gsq[tid] * (1.f / NTOT) - m * m;
        sMu[tid] = m; sRs[tid] = rsqrtf(v + 1e-5f);
        sP[tid] = poolp[tid];
    }
    __syncthreads();

    const float* hg = h2 + (size_t)g * (NG * NG);
    for (int idx = tid; idx < NG * NG; idx += 256) {
        int d = idx / NG, f = idx - (idx / NG) * NG;
        sXN[d * 91 + f] = (hg[idx] - sMu[f]) * sRs[f];
    }
    __syncthreads();

    if (tid < NG) {
        float s = 0.f;
        for (int f = 0; f < NG; f++) s += sXN[tid * 91 + f] * sP[f];
        sScore[tid] = 0.7f * tanhf(s * scal[1]);
    }
    __syncthreads();

    // wave-parallel top-10 (ties -> lower index, matching lax.top_k)
    if (tid < 64) {
        float va = sScore[tid];
        float vb = (tid + 64 < NG) ? sScore[tid + 64] : -1e30f;
        int ia = tid, ib = tid + 64;
        for (int k = 0; k < KK; k++) {
            float v; int i;
            if (va >= vb) { v = va; i = ia; } else { v = vb; i = ib; }
            for (int off = 1; off < 64; off <<= 1) {
                float v2 = __shfl_xor(v, off);
                int   i2 = __shfl_xor(i, off);
                if (v2 > v || (v2 == v && i2 < i)) { v = v2; i = i2; }
            }
            if (tid == 0) { sIdx[k] = i; sVal[k] = v; }
            if (i == ia) va = -1e30f;
            if (i == ib) vb = -1e30f;
        }
    }
    __syncthreads();

    if (tid < KK) out[NB + g * KK + tid] = (float)(g * NG + sIdx[tid]);

    float acc = 0.f;
    for (int j = tid; j < KK * NG; j += 256) {
        int k = j / NG, f = j - (j / NG) * NG;
        acc += sXN[sIdx[k] * 91 + f] * sVal[k] * vlin[j];
    }
    for (int off = 32; off; off >>= 1) acc += __shfl_down(acc, off);
    if ((tid & 63) == 0) sRed[tid >> 6] = acc;
    __syncthreads();
    if (tid == 0) {
        float tot = sRed[0] + sRed[1] + sRed[2] + sRed[3] + scal[0];
        out[g] = 1.f / (1.f + expf(-tot));
    }
}

// ---------------- host launch ----------------
extern "C" void kernel_launch(void* const* d_in, const int* in_sizes, int n_in,
                              void* d_out, int out_size, void* d_ws, size_t ws_size,
                              hipStream_t stream) {
    const float* x    = (const float*)d_in[0];
    const float* attr = (const float*)d_in[2];
    const float* W1r  = (const float*)d_in[4];
    const float* W1m  = (const float*)d_in[5];
    const float* b1   = (const float*)d_in[6];
    const float* W2r  = (const float*)d_in[7];
    const float* W2m  = (const float*)d_in[8];
    const float* b2   = (const float*)d_in[9];
    const float* poolp= (const float*)d_in[10];
    const float* linW = (const float*)d_in[11];
    const float* linb = (const float*)d_in[12];
    const float* clsW = (const float*)d_in[13];
    const float* clsb = (const float*)d_in[14];

    float* ws     = (float*)d_ws;
    float* gstats = ws;              // 384 (sum1,sq1,sum2,sq2 in 96-strides)
    float* vlin   = ws + 384;        // 900
    float* scal   = ws + 1284;       // 2
    float* h1     = ws + 2048;       // 2,073,600
    float* h2     = h1 + (size_t)NTOT * NG;

    hipMemsetAsync(gstats, 0, 384 * sizeof(float), stream);
    prep_v_kernel<<<226, 256, 0, stream>>>(linW, linb, clsW, clsb, poolp, vlin, scal);

    const size_t smem = SM_FLOATS * sizeof(float);   // 155,136 B
    layer_kernel<<<NB, 1024, smem, stream>>>(x,  gstats, 0, attr, W1m, W1r, b1, h1, gstats);
    layer_kernel<<<NB, 1024, smem, stream>>>(h1, gstats, 1, attr, W2m, W2r, b2, h2, gstats + 192);

    final_kernel<<<NB, 256, 0, stream>>>(h2, gstats + 192, gstats + 288, poolp, vlin, scal, (float*)d_out);
}